// Round 1
// baseline (171.520 us; speedup 1.0000x reference)
//
#include <hip/hip_runtime.h>

// Cubic B-spline interpolation (SplineInter), 2D, m=1024x1024, PAD=2.
// Grid: coeffs (1028 x 1028) float32, flat-clamped gather per reference.

#define I1 1028
#define TOTAL (1028 * 1028)

__device__ __forceinline__ void basis4(float t, float w[4]) {
    // j=-1: b0(4, t+1) = (1-t)^3
    float a = 1.0f - t;
    w[0] = a * a * a;
    // j=0: b0(3, t) = (3t-6)t^2 + 4
    w[1] = (3.0f * t - 6.0f) * (t * t) + 4.0f;
    // j=1: b0(2, t-1) = -(3(t-1)+6)(t-1)^2 + 4
    float xi = t - 1.0f;
    w[2] = -(3.0f * xi + 6.0f) * (xi * xi) + 4.0f;
    // j=2: b0(1, t-2) = t^3
    w[3] = t * t * t;
}

__global__ __launch_bounds__(256) void spline_interp_kernel(
    const float* __restrict__ x,      // [N,2] interleaved
    const float* __restrict__ coeffs, // [1028*1028]
    float* __restrict__ out,          // [N]
    int n)
{
    int i = blockIdx.x * blockDim.x + threadIdx.x;
    if (i >= n) return;

    // coalesced 8B load of both coords
    float2 xy = reinterpret_cast<const float2*>(x)[i];

    float xn0 = xy.x * 1024.0f - 0.5f;
    float xn1 = xy.y * 1024.0f - 0.5f;

    bool valid = (xn0 > -2.0f) && (xn0 < 1024.0f) &&
                 (xn1 > -2.0f) && (xn1 < 1024.0f);

    float P0f = floorf(xn0);
    float P1f = floorf(xn1);
    int P0 = (int)P0f;
    int P1 = (int)P1f;
    float t0 = xn0 - P0f;
    float t1 = xn1 - P1f;

    float w0[4], w1[4];
    basis4(t0, w0);
    basis4(t1, w1);

    // base flat index: i1*(PAD+P0) + (PAD+P1)
    int base = I1 * (2 + P0) + (2 + P1);

    float acc = 0.0f;
#pragma unroll
    for (int j = 0; j < 4; ++j) {
        int r = base + (j - 1) * I1 - 1;  // column offset k starts at -1
        float s = 0.0f;
#pragma unroll
        for (int k = 0; k < 4; ++k) {
            int idx = r + k;
            idx = min(max(idx, 0), TOTAL - 1);  // flat clamp, matches jnp.clip
            s = fmaf(coeffs[idx], w1[k], s);
        }
        acc = fmaf(s, w0[j], acc);
    }

    out[i] = valid ? acc : 0.0f;
}

extern "C" void kernel_launch(void* const* d_in, const int* in_sizes, int n_in,
                              void* d_out, int out_size, void* d_ws, size_t ws_size,
                              hipStream_t stream) {
    const float* x = (const float*)d_in[0];       // [N,2]
    const float* coeffs = (const float*)d_in[1];  // [1028*1028]
    float* out = (float*)d_out;                   // [N]

    int n = in_sizes[0] / 2;  // number of points
    int block = 256;
    int grid = (n + block - 1) / block;
    spline_interp_kernel<<<grid, block, 0, stream>>>(x, coeffs, out, n);
}

// Round 2
// 110.411 us; speedup vs baseline: 1.5535x; 1.5535x over previous
//
#include <hip/hip_runtime.h>

// Cubic B-spline interpolation (SplineInter), 2D, m=1024x1024, PAD=2.
// Grid: coeffs (1028 x 1028) float32, flat-clamped gather per reference.
//
// R1: row-vectorized gathers. Each stencil row = 4 consecutive floats; load
// as one dwordx4 (hardware allows dword-aligned multi-dword loads) on the
// interior fast path; exact per-element flat-clamp scalar path at edges.

#define I1 1028
#define TOTAL (1028 * 1028)

// 4-float vector with only 4-byte alignment guarantee (rows are not 16B-aligned).
typedef float f4u __attribute__((ext_vector_type(4), aligned(4)));

__device__ __forceinline__ void basis4(float t, float w[4]) {
    // j=-1: b0(4, t+1) = (1-t)^3
    float a = 1.0f - t;
    w[0] = a * a * a;
    // j=0: b0(3, t) = (3t-6)t^2 + 4
    w[1] = (3.0f * t - 6.0f) * (t * t) + 4.0f;
    // j=1: b0(2, t-1) = -(3(t-1)+6)(t-1)^2 + 4
    float xi = t - 1.0f;
    w[2] = -(3.0f * xi + 6.0f) * (xi * xi) + 4.0f;
    // j=2: b0(1, t-2) = t^3
    w[3] = t * t * t;
}

__global__ __launch_bounds__(256) void spline_interp_kernel(
    const float* __restrict__ x,      // [N,2] interleaved
    const float* __restrict__ coeffs, // [1028*1028]
    float* __restrict__ out,          // [N]
    int n)
{
    int i = blockIdx.x * blockDim.x + threadIdx.x;
    if (i >= n) return;

    float2 xy = reinterpret_cast<const float2*>(x)[i];

    float xn0 = xy.x * 1024.0f - 0.5f;
    float xn1 = xy.y * 1024.0f - 0.5f;

    bool valid = (xn0 > -2.0f) && (xn0 < 1024.0f) &&
                 (xn1 > -2.0f) && (xn1 < 1024.0f);

    float P0f = floorf(xn0);
    float P1f = floorf(xn1);
    int P0 = (int)P0f;
    int P1 = (int)P1f;
    float t0 = xn0 - P0f;
    float t1 = xn1 - P1f;

    float w0[4], w1[4];
    basis4(t0, w0);
    basis4(t1, w1);

    // base flat index: i1*(PAD+P0) + (PAD+P1)
    int base = I1 * (2 + P0) + (2 + P1);

    // Stencil spans flat indices [base - I1 - 1, base + 2*I1 + 2].
    // If fully in range, no element-wise clamp can fire -> vector fast path.
    bool interior = (base - I1 - 1 >= 0) && (base + 2 * I1 + 2 <= TOTAL - 1);

    float acc = 0.0f;
    if (interior) {
#pragma unroll
        for (int j = 0; j < 4; ++j) {
            int r = base + (j - 1) * I1 - 1;
            f4u v = *reinterpret_cast<const f4u*>(coeffs + r);
            float s = fmaf(v.x, w1[0],
                      fmaf(v.y, w1[1],
                      fmaf(v.z, w1[2],
                           v.w * w1[3])));
            acc = fmaf(s, w0[j], acc);
        }
    } else {
#pragma unroll
        for (int j = 0; j < 4; ++j) {
            int r = base + (j - 1) * I1 - 1;
            float s = 0.0f;
#pragma unroll
            for (int k = 0; k < 4; ++k) {
                int idx = r + k;
                idx = min(max(idx, 0), TOTAL - 1);  // flat clamp, matches jnp.clip
                s = fmaf(coeffs[idx], w1[k], s);
            }
            acc = fmaf(s, w0[j], acc);
        }
    }

    out[i] = valid ? acc : 0.0f;
}

extern "C" void kernel_launch(void* const* d_in, const int* in_sizes, int n_in,
                              void* d_out, int out_size, void* d_ws, size_t ws_size,
                              hipStream_t stream) {
    const float* x = (const float*)d_in[0];       // [N,2]
    const float* coeffs = (const float*)d_in[1];  // [1028*1028]
    float* out = (float*)d_out;                   // [N]

    int n = in_sizes[0] / 2;  // number of points
    int block = 256;
    int grid = (n + block - 1) / block;
    spline_interp_kernel<<<grid, block, 0, stream>>>(x, coeffs, out, n);
}

// Round 3
// 109.659 us; speedup vs baseline: 1.5641x; 1.0069x over previous
//
#include <hip/hip_runtime.h>

// Cubic B-spline interpolation (SplineInter), 2D, m=1024x1024, PAD=2.
// Grid: coeffs (1028 x 1028) float32, flat-clamped gather per reference.
//
// R1: row-vectorized gathers (4x dwordx4 per point) -> 111 -> 48 us.
// R2: 2 points per thread, all 8 row loads hoisted before the FMA chains,
//     to double per-wave memory-level parallelism (latency-hiding probe).

#define I1 1028
#define TOTAL (1028 * 1028)

// 4-float vector with only 4-byte alignment guarantee (rows are not 16B-aligned).
typedef float f4u __attribute__((ext_vector_type(4), aligned(4)));

__device__ __forceinline__ void basis4(float t, float w[4]) {
    float a = 1.0f - t;
    w[0] = a * a * a;                                // j=-1: (1-t)^3
    w[1] = (3.0f * t - 6.0f) * (t * t) + 4.0f;       // j=0
    float xi = t - 1.0f;
    w[2] = -(3.0f * xi + 6.0f) * (xi * xi) + 4.0f;   // j=1
    w[3] = t * t * t;                                // j=2
}

struct PointSetup {
    int base;
    bool valid;
    bool interior;
    float w0[4], w1[4];
};

__device__ __forceinline__ PointSetup setup_point(float2 xy) {
    PointSetup ps;
    float xn0 = xy.x * 1024.0f - 0.5f;
    float xn1 = xy.y * 1024.0f - 0.5f;

    ps.valid = (xn0 > -2.0f) && (xn0 < 1024.0f) &&
               (xn1 > -2.0f) && (xn1 < 1024.0f);

    float P0f = floorf(xn0);
    float P1f = floorf(xn1);
    int P0 = (int)P0f;
    int P1 = (int)P1f;
    float t0 = xn0 - P0f;
    float t1 = xn1 - P1f;

    basis4(t0, ps.w0);
    basis4(t1, ps.w1);

    ps.base = I1 * (2 + P0) + (2 + P1);
    // Stencil spans [base - I1 - 1, base + 2*I1 + 2]; if fully in range the
    // element-wise flat clamp can never fire.
    ps.interior = (ps.base - I1 - 1 >= 0) && (ps.base + 2 * I1 + 2 <= TOTAL - 1);
    return ps;
}

__device__ __forceinline__ float eval_slow(const float* __restrict__ coeffs,
                                           const PointSetup& ps) {
    float acc = 0.0f;
#pragma unroll
    for (int j = 0; j < 4; ++j) {
        int r = ps.base + (j - 1) * I1 - 1;
        float s = 0.0f;
#pragma unroll
        for (int k = 0; k < 4; ++k) {
            int idx = r + k;
            idx = min(max(idx, 0), TOTAL - 1);  // flat clamp, matches jnp.clip
            s = fmaf(coeffs[idx], ps.w1[k], s);
        }
        acc = fmaf(s, ps.w0[j], acc);
    }
    return acc;
}

__device__ __forceinline__ float reduce_rows(const f4u v[4], const PointSetup& ps) {
    float acc = 0.0f;
#pragma unroll
    for (int j = 0; j < 4; ++j) {
        float s = fmaf(v[j].x, ps.w1[0],
                  fmaf(v[j].y, ps.w1[1],
                  fmaf(v[j].z, ps.w1[2],
                       v[j].w * ps.w1[3])));
        acc = fmaf(s, ps.w0[j], acc);
    }
    return acc;
}

__global__ __launch_bounds__(256) void spline_interp_kernel(
    const float* __restrict__ x,      // [N,2] interleaved
    const float* __restrict__ coeffs, // [1028*1028]
    float* __restrict__ out,          // [N]
    int n, int half)
{
    int i = blockIdx.x * blockDim.x + threadIdx.x;
    if (i >= half) return;
    int i2 = i + half;

    float2 xyA = reinterpret_cast<const float2*>(x)[i];
    float2 xyB = reinterpret_cast<const float2*>(x)[i2];

    PointSetup psA = setup_point(xyA);
    PointSetup psB = setup_point(xyB);

    float accA, accB;
    if (psA.interior && psB.interior) {
        // Hoist all 8 row loads before any reduction -> 8 outstanding
        // gathers per thread.
        f4u vA[4], vB[4];
#pragma unroll
        for (int j = 0; j < 4; ++j) {
            vA[j] = *reinterpret_cast<const f4u*>(coeffs + psA.base + (j - 1) * I1 - 1);
            vB[j] = *reinterpret_cast<const f4u*>(coeffs + psB.base + (j - 1) * I1 - 1);
        }
        accA = reduce_rows(vA, psA);
        accB = reduce_rows(vB, psB);
    } else {
        accA = eval_slow(coeffs, psA);
        accB = eval_slow(coeffs, psB);
    }

    out[i]  = psA.valid ? accA : 0.0f;
    out[i2] = psB.valid ? accB : 0.0f;
}

extern "C" void kernel_launch(void* const* d_in, const int* in_sizes, int n_in,
                              void* d_out, int out_size, void* d_ws, size_t ws_size,
                              hipStream_t stream) {
    const float* x = (const float*)d_in[0];       // [N,2]
    const float* coeffs = (const float*)d_in[1];  // [1028*1028]
    float* out = (float*)d_out;                   // [N]

    int n = in_sizes[0] / 2;   // number of points (2,097,152)
    int half = n / 2;
    int block = 256;
    int grid = (half + block - 1) / block;
    spline_interp_kernel<<<grid, block, 0, stream>>>(x, coeffs, out, n, half);
}